// Round 2
// baseline (164.322 us; speedup 1.0000x reference)
//
#include <hip/hip_runtime.h>
#include <stdint.h>

// Problem constants (fixed by the reference)
#define BQ   2
#define NQ   8192
#define D1Q  128
#define D2Q  256
#define OUTQ 128
#define CATQ 384   // D1+D2
#define KQ   16

#define NBIN 4096          // 16x16x16 Morton cells
#define RED_MARGIN 1e-3f   // proxy-vs-exact bound margin (phase-1 threshold)
#define LB_MARGIN  1e-2f   // group-box lower-bound slack (covers all fp error)

// workspace byte offsets
#define WS_WFH   0          // ushort[49152]
#define WS_WFL   98304      // ushort[49152]
#define WS_HIST  196608     // u32[4][4096]  (points b0, points b1, queries b0, queries b1)
#define WS_SPXYZ 262144     // float4[2][8192] sorted points (x,y,z,npy-norm)
#define WS_QSXYZ 524288     // float4[2][8192] sorted queries (x,y,z,npy-s2)
#define WS_SPIDX 786432     // u16[2][8192] orig point idx
#define WS_QSIDX 819200     // u16[2][8192] orig query idx
#define WS_GBLO  851968     // float4[256] group AABB lo
#define WS_GBHI  856064     // float4[256] group AABB hi
// end: 860160 bytes

// bf16 split helpers (RNE)
__device__ __forceinline__ ushort f2bf(float f) {
    uint32_t u = __float_as_uint(f);
    return (ushort)((u + 0x7FFFu + ((u >> 16) & 1u)) >> 16);
}
__device__ __forceinline__ float bf2f(ushort h) {
    return __uint_as_float((uint32_t)h << 16);
}

typedef __attribute__((ext_vector_type(8))) short short8v;   // 8 bf16 (4 VGPRs)
typedef __attribute__((ext_vector_type(4))) float f32x4v;    // MFMA accumulator

// 4-bit/dim Morton bin (any binning is CORRECT; it only affects pruning rate)
__device__ __forceinline__ int mort_bin(float x, float y, float z) {
    int bx = (int)((x + 5.0f) * 1.6f); bx = bx < 0 ? 0 : (bx > 15 ? 15 : bx);
    int by = (int)((y + 5.0f) * 1.6f); by = by < 0 ? 0 : (by > 15 ? 15 : by);
    int bz = (int)((z + 5.0f) * 1.6f); bz = bz < 0 ? 0 : (bz > 15 ? 15 : bz);
    int k = 0;
    #pragma unroll
    for (int t = 0; t < 4; ++t)
        k |= (((bx >> t) & 1) << (3 * t)) | (((by >> t) & 1) << (3 * t + 1)) |
             (((bz >> t) & 1) << (3 * t + 2));
    return k;
}

// ---------------------------------------------------------------------------
// P0: W split to bf16 hi/lo in MFMA B-fragment layout + clear histograms.
// ---------------------------------------------------------------------------
__global__ void prep_w_kernel(const float* __restrict__ W,
                              ushort* __restrict__ Wfh, ushort* __restrict__ Wfl,
                              uint32_t* __restrict__ hist) {
    int flat = blockIdx.x * 256 + threadIdx.x;
    if (flat < CATQ * OUTQ) {
        int r    = flat & 7;
        int lane = (flat >> 3) & 63;
        int ctk  = flat >> 9;
        int ct   = ctk & 7;
        int kt   = ctk >> 3;
        int o = ct * 16 + (lane & 15);
        int k = kt * 32 + (lane >> 4) * 8 + r;
        float v  = W[o * CATQ + k];
        ushort h = f2bf(v);
        Wfh[flat] = h;
        Wfl[flat] = f2bf(v - bf2f(h));
    }
    if (flat < 4 * NBIN) hist[flat] = 0u;
}

// ---------------------------------------------------------------------------
// P1: Morton histograms for points (xyz1) and queries (xyz2), per batch.
// ---------------------------------------------------------------------------
__global__ void hist_kernel(const float* __restrict__ xyz1,
                            const float* __restrict__ xyz2,
                            uint32_t* __restrict__ hist) {
    int i = blockIdx.x * 256 + threadIdx.x;   // 0..32767
    if (i < BQ * NQ) {
        int batch = i >> 13;
        const float* p = xyz1 + (size_t)i * 3;
        int bin = mort_bin(p[0], p[1], p[2]);
        atomicAdd(&hist[batch * NBIN + bin], 1u);
    } else {
        int j = i - BQ * NQ;
        int batch = j >> 13;
        const float* p = xyz2 + (size_t)j * 3;
        int bin = mort_bin(p[0], p[1], p[2]);
        atomicAdd(&hist[(2 + batch) * NBIN + bin], 1u);
    }
}

// ---------------------------------------------------------------------------
// P2: exclusive prefix over each of the 4 histograms (one block per array).
// ---------------------------------------------------------------------------
__global__ void prefix_kernel(uint32_t* __restrict__ hist) {
    __shared__ uint32_t sc[1024];
    uint32_t* h = hist + (size_t)blockIdx.x * NBIN;
    int t = threadIdx.x;
    uint32_t v0 = h[4 * t], v1 = h[4 * t + 1], v2 = h[4 * t + 2], v3 = h[4 * t + 3];
    uint32_t s = v0 + v1 + v2 + v3;
    sc[t] = s;
    __syncthreads();
    for (int d = 1; d < 1024; d <<= 1) {
        uint32_t x = (t >= d) ? sc[t - d] : 0u;
        __syncthreads();
        sc[t] += x;
        __syncthreads();
    }
    uint32_t excl = sc[t] - s;
    h[4 * t]     = excl;
    h[4 * t + 1] = excl + v0;
    h[4 * t + 2] = excl + v0 + v1;
    h[4 * t + 3] = excl + v0 + v1 + v2;
}

// ---------------------------------------------------------------------------
// P3: scatter points/queries into Morton order; compute npy-exact norm / s2.
// ---------------------------------------------------------------------------
__global__ void scatter_kernel(const float* __restrict__ xyz1,
                               const float* __restrict__ xyz2,
                               uint32_t* __restrict__ hist,
                               float4* __restrict__ sp_xyzn,
                               float4* __restrict__ qs_xyzw,
                               ushort* __restrict__ sp_idx,
                               ushort* __restrict__ qs_idx) {
    int i = blockIdx.x * 256 + threadIdx.x;
    if (i < BQ * NQ) {
        int batch = i >> 13;
        const float* p = xyz1 + (size_t)i * 3;
        float x = p[0], y = p[1], z = p[2];
        int bin = mort_bin(x, y, z);
        uint32_t pos = atomicAdd(&hist[batch * NBIN + bin], 1u);
        float n;
        {
            #pragma clang fp contract(off)
            float px = x * x, py = y * y, pz = z * z;
            n = (px + py) + pz;
        }
        sp_xyzn[batch * NQ + pos] = make_float4(x, y, z, n);
        sp_idx[batch * NQ + pos]  = (ushort)(i & (NQ - 1));
    } else {
        int j = i - BQ * NQ;
        int batch = j >> 13;
        const float* p = xyz2 + (size_t)j * 3;
        float x = p[0], y = p[1], z = p[2];
        int bin = mort_bin(x, y, z);
        uint32_t pos = atomicAdd(&hist[(2 + batch) * NBIN + bin], 1u);
        float s2;
        {
            #pragma clang fp contract(off)
            float px = x * x, py = y * y, pz = z * z;
            s2 = (px + py) + pz;
        }
        qs_xyzw[batch * NQ + pos] = make_float4(x, y, z, s2);
        qs_idx[batch * NQ + pos]  = (ushort)(j & (NQ - 1));
    }
}

// ---------------------------------------------------------------------------
// P4: per-64-point-group AABBs over the sorted points. 256 groups total.
// ---------------------------------------------------------------------------
__global__ void gbox_kernel(const float4* __restrict__ sp_xyzn,
                            float4* __restrict__ gblo, float4* __restrict__ gbhi) {
    int g = blockIdx.x;            // 0..255 (global group id = batch*128 + gi)
    int lane = threadIdx.x;        // 0..63
    float4 pt = sp_xyzn[(size_t)g * 64 + lane];
    float lx = pt.x, ly = pt.y, lz = pt.z;
    float hx = pt.x, hy = pt.y, hz = pt.z;
    #pragma unroll
    for (int d = 1; d < 64; d <<= 1) {
        lx = fminf(lx, __shfl_xor(lx, d, 64));
        ly = fminf(ly, __shfl_xor(ly, d, 64));
        lz = fminf(lz, __shfl_xor(lz, d, 64));
        hx = fmaxf(hx, __shfl_xor(hx, d, 64));
        hy = fmaxf(hy, __shfl_xor(hy, d, 64));
        hz = fmaxf(hz, __shfl_xor(hz, d, 64));
    }
    if (lane == 0) {
        gblo[g] = make_float4(lx, ly, lz, 0.f);
        gbhi[g] = make_float4(hx, hy, hz, 0.f);
    }
}

// numpy-exact squared distance (same rounding as the reference BLAS path)
__device__ __forceinline__ float npy_d2(float4 pt, float qx, float qy, float qz,
                                        float s2) {
    #pragma clang fp contract(off)
    float d0  = pt.x * qx;                 // rounded product
    float dot = fmaf(pt.y, qy, d0);        // explicit FMA chain
    dot       = fmaf(pt.z, qz, dot);
    float tt  = s2 + pt.w;                 // rounded add
    return tt - 2.0f * dot;                // 2*dot exact; rounded sub
}

// 4-op reduced proxy: exact_d2 ~= s2 + red within ~1.5e-5. Phase-1 bound only.
__device__ __forceinline__ float red_r(float4 pt, float qx, float qy, float qz) {
    float dot = fmaf(pt.z, qz, fmaf(pt.y, qy, pt.x * qx));
    return fmaf(-2.0f, dot, pt.w);
}

// full ascending bitonic sort of one uint64 per lane across the wave
__device__ __forceinline__ uint64_t sort64(uint64_t x, int lane) {
    #pragma unroll
    for (int k = 2; k <= 64; k <<= 1) {
        #pragma unroll
        for (int j = k >> 1; j > 0; j >>= 1) {
            uint64_t p = __shfl_xor((unsigned long long)x, j, 64);
            bool keep_min = (((lane & j) == 0) == ((lane & k) == 0));
            bool pless    = p < x;
            x = (pless == keep_min) ? p : x;   // ties: same value either way
        }
    }
    return x;
}

// ---------------------------------------------------------------------------
// Fused kernel (R15): Morton-sorted queries AND points + group-AABB pruning.
//  - Block = 16 Morton-consecutive queries (spatially tight query box).
//  - Phase 1: proxy rank-15 threshold from a 2048-point window at the block's
//    Morton rank (bound validity unchanged; tightness much better).
//  - Phase 2: 128 group-box tests per BLOCK (thread-parallel); only surviving
//    groups get the bit-exact npy_d2 scan + compaction (machinery unchanged).
//    Skipped groups provably hold no point with d2 <= that[j]  -> selection
//    identical to the full scan.
//  - Keys carry ORIGINAL point indices (tie-break & gather unchanged).
//  - Output rows scatter through the query permutation.
// Stages 2-3 (interp gather + MFMA GEMM) unchanged from R14.
// ---------------------------------------------------------------------------
__global__ __launch_bounds__(256, 4) void fused_kernel(
        const float4* __restrict__ sp_xyzn, const ushort* __restrict__ sp_idx,
        const float4* __restrict__ qs_xyzw, const ushort* __restrict__ qs_idx,
        const float* __restrict__ points1, const float* __restrict__ points2,
        const ushort* __restrict__ Wfh, const ushort* __restrict__ Wfl,
        const float* __restrict__ bias,
        const float4* __restrict__ gblo, const float4* __restrict__ gbhi,
        float* __restrict__ out) {
    __shared__ __align__(16) char smem[33792];
    float4*   xyzt4 = (float4*)smem;                 // [0,16K)  staging
    uint64_t* wball = (uint64_t*)(smem + 16384);     // [16K,32K) [16][128]
    ushort*   pidm  = (ushort*)(smem + 32768);       // [32K,+512) chunk orig idx
    ushort*   slist = (ushort*)(smem + 33280);       // survivor group ids
    ushort*   qsl   = (ushort*)(smem + 33536);       // [16] orig query idx
    uint32_t* scntp = (uint32_t*)(smem + 33568);
    float4*   qbl   = (float4*)(smem + 33584);       // [4] per-wave query box lo
    float4*   qbh   = (float4*)(smem + 33648);       // [4] hi
    float*    thmaxA= (float*)(smem + 33712);        // [4]
    ushort*   cat_h = (ushort*)smem;                 // stages 2-3 reuse
    ushort*   cat_l = (ushort*)(smem + 12544);

    const int tid   = threadIdx.x;
    const int lane  = tid & 63;
    const int w     = tid >> 6;
    const int blk   = blockIdx.x;
    const int b     = blk >> 9;                     // batch
    const int qslot = (blk & 511) * 16;             // sorted-query base (in-batch)

    if (tid == 0) *scntp = 0u;
    if (tid < 16) qsl[tid] = qs_idx[b * NQ + qslot + tid];

    // wave's 4 sorted queries (s2 precomputed npy-exact)
    float qx[4], qy[4], qz[4], s2[4];
    int   oqi[4];
    #pragma unroll
    for (int j = 0; j < 4; ++j) {
        float4 q = qs_xyzw[(size_t)b * NQ + qslot + w * 4 + j];
        qx[j] = q.x; qy[j] = q.y; qz[j] = q.z; s2[j] = q.w;
        oqi[j] = (int)qs_idx[b * NQ + qslot + w * 4 + j];
    }
    // per-wave query bounding box
    {
        float blx = qx[0], bly = qy[0], blz = qz[0];
        float bhx = qx[0], bhy = qy[0], bhz = qz[0];
        #pragma unroll
        for (int j = 1; j < 4; ++j) {
            blx = fminf(blx, qx[j]); bly = fminf(bly, qy[j]); blz = fminf(blz, qz[j]);
            bhx = fmaxf(bhx, qx[j]); bhy = fmaxf(bhy, qy[j]); bhz = fmaxf(bhz, qz[j]);
        }
        if (lane == 0) {
            qbl[w] = make_float4(blx, bly, blz, 0.f);
            qbh[w] = make_float4(bhx, bhy, bhz, 0.f);
        }
    }

    const float4* spb = sp_xyzn + (size_t)b * NQ;
    const ushort* spi = sp_idx  + (size_t)b * NQ;

    // ------- Phase 1: proxy lane-min over a 2048-pt window at our rank -------
    int wstart = qslot + 8 - 1024;
    if (wstart < 0) wstart = 0;
    if (wstart > NQ - 2048) wstart = NQ - 2048;
    wstart &= ~63;

    float mn[4];
    #pragma unroll
    for (int j = 0; j < 4; ++j) mn[j] = __uint_as_float(0x7F800000u);

    for (int tile = 0; tile < 2; ++tile) {
        __syncthreads();
        {
            const float4* s4 = spb + wstart + tile * 1024;
            #pragma unroll
            for (int v = tid; v < 1024; v += 256) xyzt4[v] = s4[v];
        }
        __syncthreads();
        #pragma unroll 4
        for (int s = 0; s < 16; ++s) {
            float4 pt = xyzt4[s * 64 + lane];
            #pragma unroll
            for (int j = 0; j < 4; ++j)
                mn[j] = fminf(mn[j], red_r(pt, qx[j], qy[j], qz[j]));
        }
    }

    // 4 float bitonic sorts of lane minima; that[j] = s2 + rank15 + margin
    float that[4];
    #pragma unroll
    for (int j = 0; j < 4; ++j) {
        float x = mn[j];
        #pragma unroll
        for (int k = 2; k <= 64; k <<= 1) {
            #pragma unroll
            for (int jj = k >> 1; jj > 0; jj >>= 1) {
                float px = __shfl_xor(x, jj, 64);
                bool keep_min = (((lane & jj) == 0) == ((lane & k) == 0));
                float mnv = fminf(x, px), mxv = fmaxf(x, px);
                x = keep_min ? mnv : mxv;
            }
        }
        that[j] = s2[j] + __shfl(x, 15, 64) + RED_MARGIN;
    }
    {
        float tm = fmaxf(fmaxf(that[0], that[1]), fmaxf(that[2], that[3]));
        if (lane == 0) thmaxA[w] = tm;
    }
    __syncthreads();

    // ------- Group-box tests: one thread per 64-pt group, block-level -------
    if (tid < 128) {
        float4 gl = gblo[b * 128 + tid];
        float4 gh = gbhi[b * 128 + tid];
        float qlx = fminf(fminf(qbl[0].x, qbl[1].x), fminf(qbl[2].x, qbl[3].x));
        float qly = fminf(fminf(qbl[0].y, qbl[1].y), fminf(qbl[2].y, qbl[3].y));
        float qlz = fminf(fminf(qbl[0].z, qbl[1].z), fminf(qbl[2].z, qbl[3].z));
        float qhx = fmaxf(fmaxf(qbh[0].x, qbh[1].x), fmaxf(qbh[2].x, qbh[3].x));
        float qhy = fmaxf(fmaxf(qbh[0].y, qbh[1].y), fmaxf(qbh[2].y, qbh[3].y));
        float qhz = fmaxf(fmaxf(qbh[0].z, qbh[1].z), fmaxf(qbh[2].z, qbh[3].z));
        float tmax = fmaxf(fmaxf(thmaxA[0], thmaxA[1]),
                           fmaxf(thmaxA[2], thmaxA[3]));
        float dx = fmaxf(fmaxf(qlx - gh.x, gl.x - qhx), 0.f);
        float dy = fmaxf(fmaxf(qly - gh.y, gl.y - qhy), 0.f);
        float dz = fmaxf(fmaxf(qlz - gh.z, gl.z - qhz), 0.f);
        float lb = dx * dx;
        lb = fmaf(dy, dy, lb);
        lb = fmaf(dz, dz, lb);
        if (lb <= tmax + LB_MARGIN) {
            uint32_t p = atomicAdd(scntp, 1u);
            slist[p] = (ushort)tid;
        }
    }
    __syncthreads();
    const int scnt = (int)*scntp;

    // ------- Phase 2: exact scan of surviving groups (chunks of 4) -------
    uint32_t cnt[4] = {0u, 0u, 0u, 0u};
    for (int c0 = 0; c0 < scnt; c0 += 4) {
        __syncthreads();
        {
            int which = c0 + (tid >> 6);
            if (which < scnt) {
                int off = (int)slist[which] * 64 + (tid & 63);
                xyzt4[tid] = spb[off];
                pidm[tid]  = spi[off];
            }
        }
        __syncthreads();
        const int nch = (scnt - c0) < 4 ? (scnt - c0) : 4;
        for (int k = 0; k < nch; ++k) {
            float4 pt = xyzt4[k * 64 + lane];
            #pragma unroll
            for (int j = 0; j < 4; ++j) {
                float d2 = npy_d2(pt, qx[j], qy[j], qz[j], s2[j]);
                bool  v  = (d2 <= that[j]);
                uint64_t mask = __ballot((int)v);
                if (mask != 0ull) {                // scalar gate
                    if (v) {
                        uint32_t below = __builtin_amdgcn_mbcnt_hi(
                            (uint32_t)(mask >> 32),
                            __builtin_amdgcn_mbcnt_lo((uint32_t)mask, 0u));
                        uint32_t pos    = cnt[j] + below;
                        uint32_t bits   = __float_as_uint(d2);
                        uint32_t mapped = bits ^ (0x80000000u |
                                          (uint32_t)((int32_t)bits >> 31));
                        if (pos < 128u) {
                            uint32_t pidx = (uint32_t)pidm[k * 64 + lane];
                            wball[(w * 4 + j) * 128 + pos] =
                                ((uint64_t)mapped << 32) | (uint64_t)pidx;
                        }
                    }
                    cnt[j] += (uint32_t)__popcll(mask);
                }
            }
        }
    }

    // ---------------- per-query selection + weights (unchanged) ----------------
    int   myidxA[4];
    float mywgtA[4];
    #pragma unroll
    for (int j = 0; j < 4; ++j) {
        const uint64_t* wb = wball + (size_t)(w * 4 + j) * 128;
        const uint32_t c = cnt[j];
        uint64_t mykey;
        if (c <= 64u) {                            // normal path
            uint64_t k0 = (lane < (int)c) ? wb[lane] : ~0ull;
            mykey = sort64(k0, lane);
        } else {                                   // uniform fallback
            uint32_t cc = c > 128u ? 128u : c;
            uint64_t k0 = wb[lane];
            uint64_t k1 = (lane + 64 < (int)cc) ? wb[lane + 64] : ~0ull;
            k0 = sort64(k0, lane);
            k1 = sort64(k1, lane);
            uint64_t t1 = __shfl((unsigned long long)k1, lane & 15, 64);
            uint64_t km = (lane < 16) ? k0 : ((lane < 32) ? t1 : ~0ull);
            mykey = sort64(km, lane);
        }
        uint32_t mhi   = (uint32_t)(mykey >> 32);
        uint32_t rbits = (mhi & 0x80000000u) ? (mhi ^ 0x80000000u) : ~mhi;
        float    d2w   = __uint_as_float(rbits);
        myidxA[j] = (int)(uint32_t)(mykey & 0xFFFFFFFFull);
        float recip = (lane < KQ) ? (1.0f / (d2w + 1e-8f)) : 0.0f;
        float tot = recip;
        #pragma unroll
        for (int sh = 1; sh < 16; sh <<= 1) tot += __shfl_xor(tot, sh, 64);
        mywgtA[j] = recip / tot;                   // valid in lanes 0..15
    }

    // LDS reuse boundary: all waves done with xyzt4 + wball
    __syncthreads();

    // ------- Stage 2: build cat (bf16 hi/lo split) [16][392] in LDS -------
    const float* p2b = points2 + (size_t)b * NQ * D2Q;
    #pragma unroll
    for (int j = 0; j < 4; ++j) {
        const int qi = w * 4 + j;
        // p1 part: 128 floats, lanes 0..31 (orig query row via permutation)
        if (lane < 32) {
            float4 p = ((const float4*)(points1 +
                        (size_t)(b * NQ + oqi[j]) * D1Q))[lane];
            ushort4 hv, lv;
            hv.x = f2bf(p.x); lv.x = f2bf(p.x - bf2f(hv.x));
            hv.y = f2bf(p.y); lv.y = f2bf(p.y - bf2f(hv.y));
            hv.z = f2bf(p.z); lv.z = f2bf(p.z - bf2f(hv.z));
            hv.w = f2bf(p.w); lv.w = f2bf(p.w - bf2f(hv.w));
            *(ushort4*)&cat_h[qi * 392 + lane * 4] = hv;
            *(ushort4*)&cat_l[qi * 392 + lane * 4] = lv;
        }
        // interp part: 256 floats, all 64 lanes; k ascending (reference order)
        float4 acc = make_float4(0.f, 0.f, 0.f, 0.f);
        #pragma unroll
        for (int k = 0; k < KQ; ++k) {
            int   kk = __builtin_amdgcn_readlane(myidxA[j], k);
            float wk = __uint_as_float((uint32_t)__builtin_amdgcn_readlane(
                           (int)__float_as_uint(mywgtA[j]), k));
            float4 row = ((const float4*)(p2b + (size_t)kk * D2Q))[lane];
            acc.x = fmaf(wk, row.x, acc.x);
            acc.y = fmaf(wk, row.y, acc.y);
            acc.z = fmaf(wk, row.z, acc.z);
            acc.w = fmaf(wk, row.w, acc.w);
        }
        {
            ushort4 hv, lv;
            hv.x = f2bf(acc.x); lv.x = f2bf(acc.x - bf2f(hv.x));
            hv.y = f2bf(acc.y); lv.y = f2bf(acc.y - bf2f(hv.y));
            hv.z = f2bf(acc.z); lv.z = f2bf(acc.z - bf2f(hv.z));
            hv.w = f2bf(acc.w); lv.w = f2bf(acc.w - bf2f(hv.w));
            *(ushort4*)&cat_h[qi * 392 + D1Q + lane * 4] = hv;
            *(ushort4*)&cat_l[qi * 392 + D1Q + lane * 4] = lv;
        }
    }
    __syncthreads();

    // ------- Stage 3: MFMA GEMM  C[16][128] = cat[16][384] @ Wt[384][128] -------
    {
        const int arow = lane & 15;
        const int koff = (lane >> 4) * 8;
        const int ct0  = w * 2;
        f32x4v acc0 = {0.f, 0.f, 0.f, 0.f};
        f32x4v acc1 = {0.f, 0.f, 0.f, 0.f};
        #pragma unroll 4
        for (int kt = 0; kt < 12; ++kt) {
            short8v ah = *(const short8v*)&cat_h[arow * 392 + kt * 32 + koff];
            short8v al = *(const short8v*)&cat_l[arow * 392 + kt * 32 + koff];
            const ushort* bhp = Wfh + ((size_t)(kt * 8 + ct0) * 64 + lane) * 8;
            const ushort* blp = Wfl + ((size_t)(kt * 8 + ct0) * 64 + lane) * 8;
            short8v bh0 = *(const short8v*)bhp;
            short8v bl0 = *(const short8v*)blp;
            short8v bh1 = *(const short8v*)(bhp + 512);
            short8v bl1 = *(const short8v*)(blp + 512);
            acc0 = __builtin_amdgcn_mfma_f32_16x16x32_bf16(ah, bh0, acc0, 0, 0, 0);
            acc0 = __builtin_amdgcn_mfma_f32_16x16x32_bf16(al, bh0, acc0, 0, 0, 0);
            acc0 = __builtin_amdgcn_mfma_f32_16x16x32_bf16(ah, bl0, acc0, 0, 0, 0);
            acc1 = __builtin_amdgcn_mfma_f32_16x16x32_bf16(ah, bh1, acc1, 0, 0, 0);
            acc1 = __builtin_amdgcn_mfma_f32_16x16x32_bf16(al, bh1, acc1, 0, 0, 0);
            acc1 = __builtin_amdgcn_mfma_f32_16x16x32_bf16(ah, bl1, acc1, 0, 0, 0);
        }
        // C/D layout: col = lane&15, row = (lane>>4)*4 + r (m89-verified);
        // rows scatter through the query permutation.
        const int col0   = ct0 * 16 + (lane & 15);
        const int r0slot = (lane >> 4) * 4;
        const float bv0 = bias[col0];
        const float bv1 = bias[col0 + 16];
        #pragma unroll
        for (int r = 0; r < 4; ++r) {
            int oq = (int)qsl[r0slot + r];
            size_t rowoff = (size_t)(b * NQ + oq) * OUTQ;
            out[rowoff + col0]      = acc0[r] + bv0;
            out[rowoff + col0 + 16] = acc1[r] + bv1;
        }
    }
}

// ---------------------------------------------------------------------------
// Launch
// ---------------------------------------------------------------------------
extern "C" void kernel_launch(void* const* d_in, const int* in_sizes, int n_in,
                              void* d_out, int out_size, void* d_ws, size_t ws_size,
                              hipStream_t stream) {
    const float* xyz1    = (const float*)d_in[0];
    const float* xyz2    = (const float*)d_in[1];
    const float* points1 = (const float*)d_in[2];
    const float* points2 = (const float*)d_in[3];
    const float* W       = (const float*)d_in[4];
    const float* bias    = (const float*)d_in[5];

    char* ws = (char*)d_ws;
    ushort*   Wfh     = (ushort*)(ws + WS_WFH);
    ushort*   Wfl     = (ushort*)(ws + WS_WFL);
    uint32_t* hist    = (uint32_t*)(ws + WS_HIST);
    float4*   sp_xyzn = (float4*)(ws + WS_SPXYZ);
    float4*   qs_xyzw = (float4*)(ws + WS_QSXYZ);
    ushort*   sp_idx  = (ushort*)(ws + WS_SPIDX);
    ushort*   qs_idx  = (ushort*)(ws + WS_QSIDX);
    float4*   gblo    = (float4*)(ws + WS_GBLO);
    float4*   gbhi    = (float4*)(ws + WS_GBHI);

    prep_w_kernel<<<192, 256, 0, stream>>>(W, Wfh, Wfl, hist);
    hist_kernel<<<128, 256, 0, stream>>>(xyz1, xyz2, hist);
    prefix_kernel<<<4, 1024, 0, stream>>>(hist);
    scatter_kernel<<<128, 256, 0, stream>>>(xyz1, xyz2, hist,
                                            sp_xyzn, qs_xyzw, sp_idx, qs_idx);
    gbox_kernel<<<256, 64, 0, stream>>>(sp_xyzn, gblo, gbhi);
    fused_kernel<<<(BQ * NQ) / 16, 256, 0, stream>>>(
        sp_xyzn, sp_idx, qs_xyzw, qs_idx, points1, points2,
        Wfh, Wfl, bias, gblo, gbhi, (float*)d_out);
}